// Round 1
// baseline (2850.534 us; speedup 1.0000x reference)
//
#include <hip/hip_runtime.h>

#define Bb 8
#define Hh 96
#define Ww 96
#define Dd 768
#define Nn (Hh*Ww)
#define RR 3               // image rows per block
#define HGS (Hh/RR)        // 32 row-groups -> 256 blocks = 1/CU exactly
#define HALO 7             // RR+4 z2 rows staged
#define DC 16              // d-chunk floats
#define NCH (Dd/DC)        // 48
#define SZ 20              // LDS floats per token (16 data + 4 pad; 16B-aligned, coprime-ish banking)
#define ROWW 100           // 96 cols + 2 zero-pad each side
#define BUFSZ (HALO*ROWW*SZ)   // 14000 floats per buffer
#define NT 576             // 3 rows x 96 cols x 2 d-halves = 9 waves
#define TMP 0.07f

// ws layout (floats): [0]=align_sum, [1]=pos_sum, [2..9]=sum(w1[b]), [10..17]=sum(w2[b])

__global__ __launch_bounds__(256) void k_wsum(const float* __restrict__ w1,
                                              const float* __restrict__ w2,
                                              float* __restrict__ ws) {
    int j = blockIdx.x;  // 0..15
    const float* src = (j < 8 ? w1 : w2) + (size_t)(j & 7) * Nn;
    float s = 0.f;
    for (int i = threadIdx.x; i < Nn; i += 256) s += src[i];
    for (int off = 32; off > 0; off >>= 1) s += __shfl_down(s, off, 64);
    __shared__ float parts[4];
    int lane = threadIdx.x & 63, wv = threadIdx.x >> 6;
    if (lane == 0) parts[wv] = s;
    __syncthreads();
    if (threadIdx.x == 0) ws[2 + j] = parts[0] + parts[1] + parts[2] + parts[3];
    if (j == 0 && threadIdx.x == 64) ws[0] = 0.f;
    if (j == 0 && threadIdx.x == 65) ws[1] = 0.f;
}

__device__ __forceinline__ float dot4(float4 a, float4 b) {
    return a.x*b.x + a.y*b.y + a.z*b.z + a.w*b.w;
}

// one block per (b, 3-row group); 576 threads = 3 rows x 96 w-cols x 2 d-halves
__global__ __launch_bounds__(NT) void k_main(
    const float* __restrict__ z1, const float* __restrict__ z2,
    const float* __restrict__ w1, const float* __restrict__ w2,
    float* __restrict__ ws) {
  extern __shared__ float4 smdyn[];
  float* sm = (float*)smdyn;   // 2 * BUFSZ floats (112000 B)

  const int t = threadIdx.x;
  // XCD swizzle: 256 blocks = 8 XCD * 32; each XCD gets one batch b -> halo rows L2-hit
  const int nb = ((blockIdx.x & 7) << 5) | (blockIdx.x >> 3);
  const int b  = nb >> 5;            // 0..7
  const int h0 = (nb & 31) * RR;     // first image row of this block

  const int r    = t / 192;          // 0..2 (wave-uniform: 3 waves per r)
  const int rem  = t - r * 192;
  const int w    = rem % 96;
  const int half = rem / 96;         // 0..1
  const int dq   = half * 8;         // d-offset within 16-chunk

  const size_t zb = (size_t)b * Nn * Dd;
  const float* const z2b = z2 + zb;

  // --- z2 staging descriptors: 2688 float4/chunk over 576 threads -> 5 slots ---
  bool val[5]; int offl[5]; const float* gp[5];
  #pragma unroll
  for (int s = 0; s < 5; ++s) {
    int idx = t + s * NT;            // 0..2879; valid < 2688
    int rho = idx / 384;             // halo row 0..6 (7 for dead slots)
    int rm  = idx - rho * 384;
    int tok = rm >> 2, j = rm & 3;
    int hr  = h0 + rho - 2;          // image row
    bool v  = (idx < 2688) && (hr >= 0) && (hr < Hh);
    val[s]  = v;
    offl[s] = (rho * ROWW + tok + 2) * SZ + j * 4;            // 16B-aligned
    gp[s]   = z2b + (size_t)((v ? hr : 0) * Ww + tok) * Dd + j * 4;
  }
  // z1 stays in registers: this thread's own 8 floats per chunk, no LDS round-trip
  const float* g1 = z1 + zb + (size_t)((h0 + r) * Ww + w) * Dd + dq;

  // prologue: issue chunk-0 loads, zero LDS under their latency
  float4 vv[5], a0, a1, an0, an1;
  #pragma unroll
  for (int s = 0; s < 5; ++s) if (val[s]) vv[s] = *(const float4*)gp[s];
  a0 = *(const float4*)g1;
  a1 = *(const float4*)(g1 + 4);
  {
    float4 z4 = make_float4(0.f, 0.f, 0.f, 0.f);
    for (int i = t; i < 2 * BUFSZ / 4; i += NT) smdyn[i] = z4;  // pads/OOB rows stay 0 forever
  }
  __syncthreads();
  #pragma unroll
  for (int s = 0; s < 5; ++s) if (val[s]) *(float4*)&sm[offl[s]] = vv[s];
  __syncthreads();

  float acc[5][5] = {};   // [rl][k]: z2 row r+rl, image col w+k-2 (softmax is order-invariant)
  float nz2s[5]   = {};   // z2 sumsq, owned rows only (each halo row counted exactly once)
  float nz1       = 0.f;
  const int cbase = (r * ROWW + w) * SZ + dq;

  // pipeline: issue loads(c+1) -> compute(buf CUR) -> write buf CUR^1 -> barrier
#define KCHUNK(CUR, MORE) do { \
    if (MORE) { \
      _Pragma("unroll") \
      for (int s = 0; s < 5; ++s) if (val[s]) vv[s] = *(const float4*)(gp[s] + DC); \
      an0 = *(const float4*)(g1 + DC); \
      an1 = *(const float4*)(g1 + DC + 4); \
    } \
    __builtin_amdgcn_sched_barrier(0); \
    { \
      const float* bp = sm + (CUR) * BUFSZ + cbase; \
      nz1 += dot4(a0, a0) + dot4(a1, a1); \
      _Pragma("unroll") \
      for (int rl = 0; rl < 5; ++rl) { \
        const float* rp = bp + rl * (ROWW * SZ); \
        _Pragma("unroll") \
        for (int k = 0; k < 5; ++k) { \
          float4 q0 = *(const float4*)(rp + k * SZ); \
          float4 q1 = *(const float4*)(rp + k * SZ + 4); \
          acc[rl][k] += dot4(a0, q0) + dot4(a1, q1); \
          if (k == 2) { \
            bool dn = (rl <= 1) ? (r == 0) : ((rl == 2) ? true : (r == 2)); \
            if (dn) nz2s[rl] += dot4(q0, q0) + dot4(q1, q1); \
          } \
        } \
      } \
    } \
    __builtin_amdgcn_sched_barrier(0); \
    if (MORE) { \
      float* wq = sm + ((CUR) ^ 1) * BUFSZ; \
      _Pragma("unroll") \
      for (int s = 0; s < 5; ++s) if (val[s]) *(float4*)(wq + offl[s]) = vv[s]; \
      a0 = an0; a1 = an1; \
      _Pragma("unroll") \
      for (int s = 0; s < 5; ++s) gp[s] += DC; \
      g1 += DC; \
    } \
    __syncthreads(); \
  } while (0)

  for (int cc = 0; cc < NCH / 2 - 1; ++cc) {
    KCHUNK(0, true);
    KCHUNK(1, true);
  }
  KCHUNK(0, true);
  KCHUNK(1, false);
#undef KCHUNK

  // ---- cross-half reduction: alias accumulators into (dead) buffer 0 ----
  float* simS = sm;               // RR*25*96 = 7200
  float* nrm1 = sm + 7200;        // RR*96    = 288
  float* nrm2 = sm + 7488;        // HALO*96  = 672
  float* red  = sm + 8160;        // 2
  for (int i = t; i < 8162; i += NT) sm[i] = 0.f;
  __syncthreads();
  atomicAdd(&nrm1[r * 96 + w], nz1);
  #pragma unroll
  for (int rl = 0; rl < 5; ++rl) {
    bool dn = (rl <= 1) ? (r == 0) : ((rl == 2) ? true : (r == 2));
    if (dn) atomicAdd(&nrm2[(r + rl) * 96 + w], nz2s[rl]);
  }
  #pragma unroll
  for (int rl = 0; rl < 5; ++rl)
    #pragma unroll
    for (int k = 0; k < 5; ++k)
      atomicAdd(&simS[(r * 25 + rl * 5 + k) * 96 + w], acc[rl][k]);
  __syncthreads();

  if (t < RR * 96) {
    const int rr = t / 96, cw = t - rr * 96;
    const float inv1 = 1.f / fmaxf(sqrtf(nrm1[t]), 1e-12f);
    float sims[25];
    #pragma unroll
    for (int s = 0; s < 25; ++s) {
      const int rl = s / 5, k = s % 5;
      const int col = cw + k - 2;
      float vs = simS[(rr * 25 + s) * 96 + cw];
      float iv2 = 0.f;
      if (col >= 0 && col < 96) iv2 = 1.f / fmaxf(sqrtf(nrm2[(rr + rl) * 96 + col]), 1e-12f);
      sims[s] = vs * inv1 * iv2;   // OOB -> vs==0 -> 0, matches zero-pad
    }
    float m = -1e30f;
    #pragma unroll
    for (int s = 0; s < 25; ++s) m = fmaxf(m, sims[s]);
    float den = 0.f, num = 0.f;
    #pragma unroll
    for (int s = 0; s < 25; ++s) {
      float p = __expf((sims[s] - m) * (1.f / TMP));
      den += p; num += p * sims[s];
    }
    float ssb = num / den;
    int base = b * Nn + (h0 + rr) * Ww + cw;
    float wa = 0.5f * (w1[base] / (ws[2 + b] + 1e-10f) + w2[base] / (ws[10 + b] + 1e-10f));
    atomicAdd(&red[0], (1.f - ssb) * wa);
    atomicAdd(&red[1], ssb);
  }
  __syncthreads();
  if (t == 0) {
    atomicAdd(&ws[0], red[0]);
    atomicAdd(&ws[1], red[1]);
  }
}

__global__ void k_final(const float* __restrict__ ws, float* __restrict__ out) {
    if (threadIdx.x == 0) {
        out[0] = ws[0] / (float)Bb;
        out[1] = ws[1] / (float)(Bb * Nn);
    }
}

extern "C" void kernel_launch(void* const* d_in, const int* in_sizes, int n_in,
                              void* d_out, int out_size, void* d_ws, size_t ws_size,
                              hipStream_t stream) {
    const float* z1 = (const float*)d_in[0];
    const float* z2 = (const float*)d_in[1];
    const float* w1 = (const float*)d_in[2];
    const float* w2 = (const float*)d_in[3];
    float* ws = (float*)d_ws;
    float* out = (float*)d_out;

    k_wsum<<<16, 256, 0, stream>>>(w1, w2, ws);
    k_main<<<Bb * HGS, NT, (size_t)(2 * BUFSZ) * sizeof(float), stream>>>(z1, z2, w1, w2, ws);
    k_final<<<1, 64, 0, stream>>>(ws, out);
}

// Round 3
// 682.324 us; speedup vs baseline: 4.1777x; 4.1777x over previous
//
#include <hip/hip_runtime.h>

#define Bb 8
#define Hh 96
#define Ww 96
#define Dd 768
#define Nn (Hh*Ww)
#define DC 16              // floats per d-chunk
#define NCH (Dd/DC)        // 48
#define Z1W (96*DC)        // 1536 floats: z1 row block
#define Z2W (5*96*DC)      // 7680 floats: 5 halo rows
#define BUFSZ (Z1W+Z2W)    // 9216 floats per buffer; x2 buffers = 73728 B LDS
#define NT 384             // 96 cols x 4 d-quarters
#define TMP 0.07f

// ws layout (floats): [0]=align_sum, [1]=pos_sum, [2..9]=sum(w1[b]), [10..17]=sum(w2[b])

__global__ __launch_bounds__(256) void k_wsum(const float* __restrict__ w1,
                                              const float* __restrict__ w2,
                                              float* __restrict__ ws) {
    int j = blockIdx.x;  // 0..15
    const float* src = (j < 8 ? w1 : w2) + (size_t)(j & 7) * Nn;
    float s = 0.f;
    for (int i = threadIdx.x; i < Nn; i += 256) s += src[i];
    for (int off = 32; off > 0; off >>= 1) s += __shfl_down(s, off, 64);
    __shared__ float parts[4];
    int lane = threadIdx.x & 63, wv = threadIdx.x >> 6;
    if (lane == 0) parts[wv] = s;
    __syncthreads();
    if (threadIdx.x == 0) ws[2 + j] = parts[0] + parts[1] + parts[2] + parts[3];
    if (j == 0 && threadIdx.x == 64) ws[0] = 0.f;
    if (j == 0 && threadIdx.x == 65) ws[1] = 0.f;
}

__device__ __forceinline__ void gload16(const float* g, float* l) {
    __builtin_amdgcn_global_load_lds((const __attribute__((address_space(1))) void*)g,
                                     (__attribute__((address_space(3))) void*)l,
                                     16, 0, 0);
}

__device__ __forceinline__ float dot4(float4 a, float4 b) {
    return a.x*b.x + a.y*b.y + a.z*b.z + a.w*b.w;
}

// one block per (b,h); 384 threads = 96 w-columns x 4 d-quarters.
// LDS layout is LINEAR token-major [token][16 floats] (global_load_lds requires it),
// with the d-quarter slot XOR-swizzled: quarter q of token T sits in slot j = q ^ ((T>>1)&3).
// -> bank-group of a b128 read = (4(T&1)+j)%8 is uniform over consecutive tokens: conflict-free.
// Swizzle applied on BOTH sides (guideline 21): global source fetches quarter j^((T>>1)&3)
// (stays inside the same 64B line -> coalescing unchanged), compute reads slot q^((T>>1)&3).
__global__ __launch_bounds__(NT) void k_main(
    const float* __restrict__ z1, const float* __restrict__ z2,
    const float* __restrict__ w1, const float* __restrict__ w2,
    float* __restrict__ ws) {
  extern __shared__ float sm[];

  const int t = threadIdx.x;
  const int b = blockIdx.x & 7;          // == XCD id (blocks round-robin XCDs) -> halo rows L2-hit
  const int h = blockIdx.x >> 3;         // image row 0..95

  const int w       = t % 96;
  const int quarter = t / 96;            // this thread computes d = quarter*4..+3 of each chunk

  // ---- staging descriptors: thread t stages token Ts, LDS slot t&3, global quarter qs ----
  const int Ts = t >> 2;
  const int qs = (t & 3) ^ ((Ts >> 1) & 3);
  const size_t zb = (size_t)b * Nn * Dd;
  const float* z1p = z1 + zb + (size_t)(h*Ww + Ts)*Dd + qs*4;
  const float* z2r[5];
  #pragma unroll
  for (int rep = 0; rep < 5; ++rep) {
    int r_ = h + rep - 2;                // halo image row; clamp OOB (finite garbage, masked in epilogue)
    r_ = r_ < 0 ? 0 : (r_ > Hh-1 ? Hh-1 : r_);
    z2r[rep] = z2 + zb + (size_t)(r_*Ww + Ts)*Dd + qs*4;
  }

  // ---- compute-read offsets (floats), swizzle-matched ----
  const int aoff = w*DC + 4*(quarter ^ ((w >> 1) & 3));
  int coff[5];
  #pragma unroll
  for (int k = 0; k < 5; ++k) {
    int T2 = w + k - 2;                  // image col; clamp OOB (masked in epilogue)
    T2 = T2 < 0 ? 0 : (T2 > 95 ? 95 : T2);
    coff[k] = T2*DC + 4*(quarter ^ ((T2 >> 1) & 3));
  }

  auto stage = [&](int cc) {             // 6 global_load_lds per thread, zero data VGPRs
    float* dst = sm + (cc & 1) * BUFSZ;
    const int dof = cc * DC;
    gload16(z1p + dof, dst + t*4);       // dest = wave-uniform base + lane*16B: OK for gload_lds
    #pragma unroll
    for (int rep = 0; rep < 5; ++rep)
      gload16(z2r[rep] + dof, dst + Z1W + (t + rep*NT)*4);
  };

  float acc[5][5] = {};   // [rho][k]: z2 row h+rho-2, image col w+k-2
  float nz2a[5]   = {};
  float nz1       = 0.f;

  auto compute = [&](int cc) {
    const float* bp = sm + (cc & 1) * BUFSZ;
    const float4 a = *(const float4*)(bp + aoff);
    nz1 += dot4(a, a);
    #pragma unroll
    for (int rho = 0; rho < 5; ++rho) {
      #pragma unroll
      for (int k = 0; k < 5; ++k) {
        const float4 q = *(const float4*)(bp + Z1W + rho*(96*DC) + coff[k]);
        acc[rho][k] += dot4(a, q);
        if (k == 2) nz2a[rho] += dot4(q, q);   // T2==w here, never clamped -> exact norms
      }
    }
  };

  // ---- canonical 2-phase pipeline (T3 minimum): issue next loads, compute current, full drain ----
  stage(0);
  __syncthreads();                       // chunk 0 landed + visible
  for (int c = 0; c < NCH-1; ++c) {
    stage(c+1);                          // issue into buf[(c+1)&1]; latency hides under compute(c)
    compute(c);                          // 26 ds_read_b128 + 124 FMAs per thread
    __syncthreads();                     // drains vmcnt+lgkmcnt: chunk c+1 ready, buf[c&1] releasable
  }
  compute(NCH-1);
  __syncthreads();                       // all reads retired; safe to reuse LDS

  // ---- cross-quarter reduction (alias dead LDS) ----
  float* simS = sm;               // 25*96 = 2400
  float* nrm1 = sm + 2400;        // 96
  float* nrm2 = nrm1 + 96;        // 5*96 = 480
  float* red  = nrm2 + 480;       // 2
  for (int i = t; i < 2978; i += NT) sm[i] = 0.f;
  __syncthreads();
  atomicAdd(&nrm1[w], nz1);
  #pragma unroll
  for (int rho = 0; rho < 5; ++rho) atomicAdd(&nrm2[rho*96 + w], nz2a[rho]);
  #pragma unroll
  for (int rho = 0; rho < 5; ++rho)
    #pragma unroll
    for (int k = 0; k < 5; ++k)
      atomicAdd(&simS[(rho*5 + k)*96 + w], acc[rho][k]);
  __syncthreads();

  if (t < 96) {
    const float inv1 = 1.f / fmaxf(sqrtf(nrm1[t]), 1e-12f);
    float sims[25];
    #pragma unroll
    for (int s = 0; s < 25; ++s) {
      const int rho = s / 5, k = s % 5;
      const int col = t + k - 2;
      const int row = h + rho - 2;
      const bool ok = (col >= 0) && (col < Ww) && (row >= 0) && (row < Hh);
      float v = simS[s*96 + t];
      float iv2 = ok ? 1.f / fmaxf(sqrtf(nrm2[rho*96 + (ok ? col : 0)]), 1e-12f) : 0.f;
      sims[s] = ok ? v * inv1 * iv2 : 0.f;   // OOB shift -> sim exactly 0, matches zero-pad reference
    }
    float m = -1e30f;
    #pragma unroll
    for (int s = 0; s < 25; ++s) m = fmaxf(m, sims[s]);
    float den = 0.f, num = 0.f;
    #pragma unroll
    for (int s = 0; s < 25; ++s) {
      float p = __expf((sims[s] - m) * (1.f / TMP));
      den += p; num += p * sims[s];
    }
    float ssb = num / den;
    int base = b*Nn + h*Ww + t;
    float wa = 0.5f * (w1[base] / (ws[2 + b] + 1e-10f) + w2[base] / (ws[10 + b] + 1e-10f));
    atomicAdd(&red[0], (1.f - ssb) * wa);
    atomicAdd(&red[1], ssb);
  }
  __syncthreads();
  if (t == 0) {
    atomicAdd(&ws[0], red[0]);
    atomicAdd(&ws[1], red[1]);
  }
}

__global__ void k_final(const float* __restrict__ ws, float* __restrict__ out) {
    if (threadIdx.x == 0) {
        out[0] = ws[0] / (float)Bb;
        out[1] = ws[1] / (float)(Bb * Nn);
    }
}

extern "C" void kernel_launch(void* const* d_in, const int* in_sizes, int n_in,
                              void* d_out, int out_size, void* d_ws, size_t ws_size,
                              hipStream_t stream) {
    const float* z1 = (const float*)d_in[0];
    const float* z2 = (const float*)d_in[1];
    const float* w1 = (const float*)d_in[2];
    const float* w2 = (const float*)d_in[3];
    float* ws = (float*)d_ws;
    float* out = (float*)d_out;

    k_wsum<<<16, 256, 0, stream>>>(w1, w2, ws);
    k_main<<<Bb*Hh, NT, (size_t)(2*BUFSZ)*sizeof(float), stream>>>(z1, z2, w1, w2, ws);
    k_final<<<1, 64, 0, stream>>>(ws, out);
}